// Round 17
// baseline (127.246 us; speedup 1.0000x reference)
//
#include <hip/hip_runtime.h>
#include <math.h>

// FaceKernelCorrelation: B=8, N=16384, K=64, 4 kernel pts per k, sigma=0.2
// R17: base = R12 (proven 48.1us: packed v_pk_fma chains + v_exp_f32,
// lb(256,7), 3-kernel). ONE change: sT stats tile packed to bf16
// (uint[4][64][9], 2 k's per u32, RNE) -> LDS 21504 -> 13312 B. With
// VGPR=36 actual, LDS was the ONLY thing capping residency at 7 blocks/CU
// (21.5K*8=172K>160K); now 8 blocks/CU (32 waves = CU cap) fit.
// NOTE lb stays (256,7): the 2nd arg only caps the allocator (<=72 VGPR);
// runtime occupancy is set by actual VGPR/LDS. NEVER lb(256,8) [R11/R13:
// allocator spills -> FETCH/WRITE blowup, 5x slower]. Poly-exp abandoned
// [R16: poly busy 33us > v_exp busy 22us — trans pipe shares issue port].
// bf16 stats pack validated correct in R13 (passed, absmax 0.0625).
//  1) kc_kernel:  gather fea, kc -> out + fused per-block stats partials.
//  2) fin_kernel: 64 blocks: reduce 2048 partials -> scale/shift.
//  3) bn_kernel:  in-place float4 y = relu(kc*scale + shift).

#define NFACES 16384
#define BATCH  8
#define KK     64
#define NBLK   2048            // kc grid: BATCH * (NFACES/64)

typedef float v2f __attribute__((ext_vector_type(2)));

// C = -1/(2*sigma^2) * log2(e)  with sigma = 0.2
__device__ __constant__ const float C_SCALE = -18.033688011112043f;

__device__ __forceinline__ unsigned int bf16_rne(float x) {
    unsigned int b = __builtin_bit_cast(unsigned int, x);
    return (b + 0x7FFFu + ((b >> 16) & 1u)) >> 16;
}

__global__ __launch_bounds__(256, 7) void kc_kernel(
    const float* __restrict__ normals,   // [B,3,N]
    const int*   __restrict__ nbr,       // [B,N,3]
    const float* __restrict__ walpha,    // [K*4]
    const float* __restrict__ wbeta,     // [K*4]
    float*       __restrict__ out,       // [B,K,N]
    float*       __restrict__ psum,      // [K][NBLK]
    float*       __restrict__ psumsq)    // [K][NBLK]
{
    __shared__ float4 sW[KK * 4];          // (m2*wx, m2*wy, m2*wz, 0)  4096 B
    __shared__ unsigned int sTp[4][64][9]; // [wave][lane][k-pair] bf16x2 9216 B

    const int tid = threadIdx.x;

    // Kernel-point table: 256 threads -> 256 (k,j) entries
    {
        float a = walpha[tid];
        float b = wbeta[tid];
        float sa = sinf(a), ca = cosf(a);
        float sb = sinf(b), cb = cosf(b);
        const float m2 = -2.0f * C_SCALE;
        sW[tid] = make_float4(m2 * sa * cb, m2 * sa * sb, m2 * ca, 0.0f);
    }
    __syncthreads();

    const int b    = blockIdx.x >> 8;
    const int lane = tid & 63;
    const int n    = ((blockIdx.x & 255) << 6) + lane;
    const int kq   = tid >> 6;

    const float* nb_ = normals + (size_t)b * 3 * NFACES;
    float fx[4], fy[4], fz[4];
    fx[0] = nb_[n];
    fy[0] = nb_[NFACES + n];
    fz[0] = nb_[2 * NFACES + n];
    const int* ip = nbr + ((size_t)b * NFACES + n) * 3;
#pragma unroll
    for (int j = 0; j < 3; ++j) {
        int idx = ip[j];
        fx[j + 1] = nb_[idx];
        fy[j + 1] = nb_[NFACES + idx];
        fz[j + 1] = nb_[2 * NFACES + idx];
    }

    // Pack the 4 fea points into float2 pairs for v_pk_fma_f32.
    v2f fx01 = {fx[0], fx[1]}, fx23 = {fx[2], fx[3]};
    v2f fy01 = {fy[0], fy[1]}, fy23 = {fy[2], fy[3]};
    v2f fz01 = {fz[0], fz[1]}, fz23 = {fz[2], fz[3]};
    // fa_i = C*(|f_i|^2 + |w|^2), |w|^2 == 1 (to 1ulp)  — chain init
    v2f fa01, fa23;
    {
        v2f n01 = fx01 * fx01 + fy01 * fy01 + fz01 * fz01;
        v2f n23 = fx23 * fx23 + fy23 * fy23 + fz23 * fz23;
        fa01 = (v2f){C_SCALE, C_SCALE} * n01 + (v2f){C_SCALE, C_SCALE};
        fa23 = (v2f){C_SCALE, C_SCALE} * n23 + (v2f){C_SCALE, C_SCALE};
    }

    float* outp = out + ((size_t)b * KK + kq * 16) * NFACES + n;
    const float4* wp = &sW[kq * 64];

    unsigned int kc_even = 0;            // bf16 of even-kk kc, pending pack

#pragma unroll
    for (int kk = 0; kk < 16; ++kk) {
        float s0 = 0.0f, s1 = 0.0f, s2 = 0.0f, s3 = 0.0f;
#pragma unroll
        for (int j = 0; j < 4; ++j) {
            float4 w = wp[kk * 4 + j];
            v2f wx = {w.x, w.x}, wy = {w.y, w.y}, wz = {w.z, w.z};
            v2f t01 = __builtin_elementwise_fma(wx, fx01,
                        __builtin_elementwise_fma(wy, fy01,
                          __builtin_elementwise_fma(wz, fz01, fa01)));
            v2f t23 = __builtin_elementwise_fma(wx, fx23,
                        __builtin_elementwise_fma(wy, fy23,
                          __builtin_elementwise_fma(wz, fz23, fa23)));
            s0 += __builtin_amdgcn_exp2f(t01.x);
            s1 += __builtin_amdgcn_exp2f(t01.y);
            s2 += __builtin_amdgcn_exp2f(t23.x);
            s3 += __builtin_amdgcn_exp2f(t23.y);
        }
        float kc = ((s0 + s1) + (s2 + s3)) * 0.0625f;
        outp[(size_t)kk * NFACES] = kc;

        if ((kk & 1) == 0) {
            kc_even = bf16_rne(kc);
        } else {
            sTp[kq][lane][kk >> 1] = kc_even | (bf16_rne(kc) << 16);
        }
    }

    // Per-wave transpose reduce: thread (kk,seg) sums 16 bf16 values.
    {
        const int kk = lane & 15, seg = lane >> 4;
        const int kkp = kk >> 1;
        const unsigned int mask = (kk & 1) ? 0xFFFF0000u : 0x0000FFFFu;
        const int          shl  = (kk & 1) ? 0 : 16;
        float v = 0.0f, q = 0.0f;
#pragma unroll
        for (int j = 0; j < 16; ++j) {
            unsigned int u = sTp[kq][seg * 16 + j][kkp];
            float x = __builtin_bit_cast(float, (u & mask) << shl);
            v += x;
            q = __builtin_fmaf(x, x, q);
        }
        v += __shfl_xor(v, 16, 64);  q += __shfl_xor(q, 16, 64);
        v += __shfl_xor(v, 32, 64);  q += __shfl_xor(q, 32, 64);
        if (seg == 0) {
            const int k = kq * 16 + kk;
            psum[(size_t)k * NBLK + blockIdx.x]   = v;
            psumsq[(size_t)k * NBLK + blockIdx.x] = q;
        }
    }
}

// One block per k: reduce 2048 partials -> scale/shift.
__global__ __launch_bounds__(256) void fin_kernel(
    const float* __restrict__ psum,
    const float* __restrict__ psumsq,
    const float* __restrict__ gamma,
    const float* __restrict__ beta,
    float*       __restrict__ scale,
    float*       __restrict__ shift)
{
    const int k = blockIdx.x;
    const int tid = threadIdx.x;
    const float4* ps = reinterpret_cast<const float4*>(psum   + (size_t)k * NBLK);
    const float4* pq = reinterpret_cast<const float4*>(psumsq + (size_t)k * NBLK);

    float s = 0.0f, q = 0.0f;
#pragma unroll
    for (int i = 0; i < 2; ++i) {
        float4 a = ps[i * 256 + tid];
        float4 c = pq[i * 256 + tid];
        s += (a.x + a.y) + (a.z + a.w);
        q += (c.x + c.y) + (c.z + c.w);
    }

    __shared__ float sS[4], sQ[4];
#pragma unroll
    for (int off = 32; off > 0; off >>= 1) {
        s += __shfl_down(s, off, 64);
        q += __shfl_down(q, off, 64);
    }
    const int lane = tid & 63, wid = tid >> 6;
    if (lane == 0) { sS[wid] = s; sQ[wid] = q; }
    __syncthreads();
    if (tid == 0) {
        float sum = (sS[0] + sS[1]) + (sS[2] + sS[3]);
        float sq  = (sQ[0] + sQ[1]) + (sQ[2] + sQ[3]);
        const float invN = 1.0f / (float)(BATCH * NFACES);
        float mean = sum * invN;
        float var  = sq * invN - mean * mean;
        float sc = gamma[k] / sqrtf(var + 1e-5f);
        scale[k] = sc;
        shift[k] = beta[k] - mean * sc;
    }
}

__global__ __launch_bounds__(256) void bn_kernel(
    float* __restrict__ out,
    const float* __restrict__ scale,
    const float* __restrict__ shift)
{
    const size_t idx = (size_t)blockIdx.x * 256 + threadIdx.x;
    const int k = (int)((idx >> 12) & 63);
    float4 v = reinterpret_cast<float4*>(out)[idx];
    const float sc = scale[k], sh = shift[k];
    v.x = fmaxf(__builtin_fmaf(v.x, sc, sh), 0.0f);
    v.y = fmaxf(__builtin_fmaf(v.y, sc, sh), 0.0f);
    v.z = fmaxf(__builtin_fmaf(v.z, sc, sh), 0.0f);
    v.w = fmaxf(__builtin_fmaf(v.w, sc, sh), 0.0f);
    reinterpret_cast<float4*>(out)[idx] = v;
}

extern "C" void kernel_launch(void* const* d_in, const int* in_sizes, int n_in,
                              void* d_out, int out_size, void* d_ws, size_t ws_size,
                              hipStream_t stream) {
    const float* normals = (const float*)d_in[0];
    const int*   nbr     = (const int*)d_in[1];
    const float* walpha  = (const float*)d_in[2];
    const float* wbeta   = (const float*)d_in[3];
    const float* gamma   = (const float*)d_in[4];
    const float* beta    = (const float*)d_in[5];
    float* out = (float*)d_out;

    float* psum   = (float*)d_ws;              // [64][2048]
    float* psumsq = psum + KK * NBLK;          // [64][2048]
    float* scale  = psumsq + KK * NBLK;        // [64]
    float* shift  = scale + KK;                // [64]

    kc_kernel<<<NBLK, 256, 0, stream>>>(normals, nbr, walpha, wbeta, out, psum, psumsq);
    fin_kernel<<<KK, 256, 0, stream>>>(psum, psumsq, gamma, beta, scale, shift);

    const int total_f4 = (BATCH * KK * NFACES) / 4;   // 2,097,152
    bn_kernel<<<total_f4 / 256, 256, 0, stream>>>(out, scale, shift);
}

// Round 18
// 49.241 us; speedup vs baseline: 2.5841x; 2.5841x over previous
//
#include <hip/hip_runtime.h>
#include <math.h>

// FaceKernelCorrelation: B=8, N=16384, K=64, 4 kernel pts per k, sigma=0.2
// R18: base = R12 (proven 48.1us). ONE change: sT stats tile made exact-fit
// so 8 blocks/CU become resident (LDS was the only cap: 21504*8 > 160K).
//   sT: f32 [4][64][17] (+1 pad, 17408B) -> f32 [4][64][16] (16384B) with a
//   ROTATION swizzle col=(kk+row)&15 for bank spreading (4-way on write and
//   read, ~1.6x on 16 LDS ops = ~+100cyc/wave — noise vs +1 wave/SIMD TLP).
//   Total LDS: 4096(sW) + 16384 = 20480 = exactly 160K/8.
// BANNED by evidence:
//   - bf16 sT pack [R13+R17: both -> scratch blowup (FETCH/WRITE 100s of MB),
//     independent of launch bounds; codegen pathology]
//   - lb(256,8) [R11: coop spill], poly-exp [R16: slower than v_exp],
//     coop single-kernel [R11: 293us].
//  1) kc_kernel:  gather fea, kc -> out + fused per-block stats partials.
//  2) fin_kernel: 64 blocks: reduce 2048 partials -> scale/shift.
//  3) bn_kernel:  in-place float4 y = relu(kc*scale + shift).

#define NFACES 16384
#define BATCH  8
#define KK     64
#define NBLK   2048            // kc grid: BATCH * (NFACES/64)

typedef float v2f __attribute__((ext_vector_type(2)));

// C = -1/(2*sigma^2) * log2(e)  with sigma = 0.2
__device__ __constant__ const float C_SCALE = -18.033688011112043f;

__global__ __launch_bounds__(256, 7) void kc_kernel(
    const float* __restrict__ normals,   // [B,3,N]
    const int*   __restrict__ nbr,       // [B,N,3]
    const float* __restrict__ walpha,    // [K*4]
    const float* __restrict__ wbeta,     // [K*4]
    float*       __restrict__ out,       // [B,K,N]
    float*       __restrict__ psum,      // [K][NBLK]
    float*       __restrict__ psumsq)    // [K][NBLK]
{
    __shared__ float4 sW[KK * 4];        // (m2*wx, m2*wy, m2*wz, 0)   4096 B
    __shared__ float  sT[4][64][16];     // rotation-swizzled tile    16384 B

    const int tid = threadIdx.x;

    // Kernel-point table: 256 threads -> 256 (k,j) entries
    {
        float a = walpha[tid];
        float b = wbeta[tid];
        float sa = sinf(a), ca = cosf(a);
        float sb = sinf(b), cb = cosf(b);
        const float m2 = -2.0f * C_SCALE;
        sW[tid] = make_float4(m2 * sa * cb, m2 * sa * sb, m2 * ca, 0.0f);
    }
    __syncthreads();

    const int b    = blockIdx.x >> 8;
    const int lane = tid & 63;
    const int n    = ((blockIdx.x & 255) << 6) + lane;
    const int kq   = tid >> 6;

    const float* nb_ = normals + (size_t)b * 3 * NFACES;
    float fx[4], fy[4], fz[4];
    fx[0] = nb_[n];
    fy[0] = nb_[NFACES + n];
    fz[0] = nb_[2 * NFACES + n];
    const int* ip = nbr + ((size_t)b * NFACES + n) * 3;
#pragma unroll
    for (int j = 0; j < 3; ++j) {
        int idx = ip[j];
        fx[j + 1] = nb_[idx];
        fy[j + 1] = nb_[NFACES + idx];
        fz[j + 1] = nb_[2 * NFACES + idx];
    }

    // Pack the 4 fea points into float2 pairs for v_pk_fma_f32.
    v2f fx01 = {fx[0], fx[1]}, fx23 = {fx[2], fx[3]};
    v2f fy01 = {fy[0], fy[1]}, fy23 = {fy[2], fy[3]};
    v2f fz01 = {fz[0], fz[1]}, fz23 = {fz[2], fz[3]};
    // fa_i = C*(|f_i|^2 + |w|^2), |w|^2 == 1 (to 1ulp)  — chain init
    v2f fa01, fa23;
    {
        v2f n01 = fx01 * fx01 + fy01 * fy01 + fz01 * fz01;
        v2f n23 = fx23 * fx23 + fy23 * fy23 + fz23 * fz23;
        fa01 = (v2f){C_SCALE, C_SCALE} * n01 + (v2f){C_SCALE, C_SCALE};
        fa23 = (v2f){C_SCALE, C_SCALE} * n23 + (v2f){C_SCALE, C_SCALE};
    }

    float* outp = out + ((size_t)b * KK + kq * 16) * NFACES + n;
    const float4* wp = &sW[kq * 64];

#pragma unroll
    for (int kk = 0; kk < 16; ++kk) {
        float s0 = 0.0f, s1 = 0.0f, s2 = 0.0f, s3 = 0.0f;
#pragma unroll
        for (int j = 0; j < 4; ++j) {
            float4 w = wp[kk * 4 + j];
            v2f wx = {w.x, w.x}, wy = {w.y, w.y}, wz = {w.z, w.z};
            v2f t01 = __builtin_elementwise_fma(wx, fx01,
                        __builtin_elementwise_fma(wy, fy01,
                          __builtin_elementwise_fma(wz, fz01, fa01)));
            v2f t23 = __builtin_elementwise_fma(wx, fx23,
                        __builtin_elementwise_fma(wy, fy23,
                          __builtin_elementwise_fma(wz, fz23, fa23)));
            s0 += __builtin_amdgcn_exp2f(t01.x);
            s1 += __builtin_amdgcn_exp2f(t01.y);
            s2 += __builtin_amdgcn_exp2f(t23.x);
            s3 += __builtin_amdgcn_exp2f(t23.y);
        }
        float kc = ((s0 + s1) + (s2 + s3)) * 0.0625f;
        outp[(size_t)kk * NFACES] = kc;
        sT[kq][lane][(kk + lane) & 15] = kc;   // rotation swizzle, intra-wave
    }

    // Per-wave transpose reduce: thread (kk,seg) sums rows seg*16+j, col kk
    // (stored at swizzled col (kk+j)&15 since row&15 == j).
    {
        const int kk = lane & 15, seg = lane >> 4;
        float v = 0.0f, q = 0.0f;
#pragma unroll
        for (int j = 0; j < 16; ++j) {
            float x = sT[kq][seg * 16 + j][(kk + j) & 15];
            v += x;
            q = __builtin_fmaf(x, x, q);
        }
        v += __shfl_xor(v, 16, 64);  q += __shfl_xor(q, 16, 64);
        v += __shfl_xor(v, 32, 64);  q += __shfl_xor(q, 32, 64);
        if (seg == 0) {
            const int k = kq * 16 + kk;
            psum[(size_t)k * NBLK + blockIdx.x]   = v;
            psumsq[(size_t)k * NBLK + blockIdx.x] = q;
        }
    }
}

// One block per k: reduce 2048 partials -> scale/shift.
__global__ __launch_bounds__(256) void fin_kernel(
    const float* __restrict__ psum,
    const float* __restrict__ psumsq,
    const float* __restrict__ gamma,
    const float* __restrict__ beta,
    float*       __restrict__ scale,
    float*       __restrict__ shift)
{
    const int k = blockIdx.x;
    const int tid = threadIdx.x;
    const float4* ps = reinterpret_cast<const float4*>(psum   + (size_t)k * NBLK);
    const float4* pq = reinterpret_cast<const float4*>(psumsq + (size_t)k * NBLK);

    float s = 0.0f, q = 0.0f;
#pragma unroll
    for (int i = 0; i < 2; ++i) {
        float4 a = ps[i * 256 + tid];
        float4 c = pq[i * 256 + tid];
        s += (a.x + a.y) + (a.z + a.w);
        q += (c.x + c.y) + (c.z + c.w);
    }

    __shared__ float sS[4], sQ[4];
#pragma unroll
    for (int off = 32; off > 0; off >>= 1) {
        s += __shfl_down(s, off, 64);
        q += __shfl_down(q, off, 64);
    }
    const int lane = tid & 63, wid = tid >> 6;
    if (lane == 0) { sS[wid] = s; sQ[wid] = q; }
    __syncthreads();
    if (tid == 0) {
        float sum = (sS[0] + sS[1]) + (sS[2] + sS[3]);
        float sq  = (sQ[0] + sQ[1]) + (sQ[2] + sQ[3]);
        const float invN = 1.0f / (float)(BATCH * NFACES);
        float mean = sum * invN;
        float var  = sq * invN - mean * mean;
        float sc = gamma[k] / sqrtf(var + 1e-5f);
        scale[k] = sc;
        shift[k] = beta[k] - mean * sc;
    }
}

__global__ __launch_bounds__(256) void bn_kernel(
    float* __restrict__ out,
    const float* __restrict__ scale,
    const float* __restrict__ shift)
{
    const size_t idx = (size_t)blockIdx.x * 256 + threadIdx.x;
    const int k = (int)((idx >> 12) & 63);
    float4 v = reinterpret_cast<float4*>(out)[idx];
    const float sc = scale[k], sh = shift[k];
    v.x = fmaxf(__builtin_fmaf(v.x, sc, sh), 0.0f);
    v.y = fmaxf(__builtin_fmaf(v.y, sc, sh), 0.0f);
    v.z = fmaxf(__builtin_fmaf(v.z, sc, sh), 0.0f);
    v.w = fmaxf(__builtin_fmaf(v.w, sc, sh), 0.0f);
    reinterpret_cast<float4*>(out)[idx] = v;
}

extern "C" void kernel_launch(void* const* d_in, const int* in_sizes, int n_in,
                              void* d_out, int out_size, void* d_ws, size_t ws_size,
                              hipStream_t stream) {
    const float* normals = (const float*)d_in[0];
    const int*   nbr     = (const int*)d_in[1];
    const float* walpha  = (const float*)d_in[2];
    const float* wbeta   = (const float*)d_in[3];
    const float* gamma   = (const float*)d_in[4];
    const float* beta    = (const float*)d_in[5];
    float* out = (float*)d_out;

    float* psum   = (float*)d_ws;              // [64][2048]
    float* psumsq = psum + KK * NBLK;          // [64][2048]
    float* scale  = psumsq + KK * NBLK;        // [64]
    float* shift  = scale + KK;                // [64]

    kc_kernel<<<NBLK, 256, 0, stream>>>(normals, nbr, walpha, wbeta, out, psum, psumsq);
    fin_kernel<<<KK, 256, 0, stream>>>(psum, psumsq, gamma, beta, scale, shift);

    const int total_f4 = (BATCH * KK * NFACES) / 4;   // 2,097,152
    bn_kernel<<<total_f4 / 256, 256, 0, stream>>>(out, scale, shift);
}

// Round 19
// 48.041 us; speedup vs baseline: 2.6487x; 1.0250x over previous
//
#include <hip/hip_runtime.h>
#include <math.h>

// FaceKernelCorrelation: B=8, N=16384, K=64, 4 kernel pts per k, sigma=0.2
// R19: FINAL — exact revert to R12 (best measured: 48.1us). kc is at its
// issue-port floor (validated model, all vector ops serialize on the SIMD
// issue port): v_exp_f32 ~33 issue-cyc/wave64 x 256 exps x 8 waves + ~1700
// VALU cyc = 81K cyc/SIMD = 34us — matches measurement within 2%. The 134M
// exps are algebraically irreducible (exp factoring overflows: t=-18(|f|-1)^2
// splits into fa~-560 + dot~+520); poly-exp measured 1.5x MORE issue-cycles
// (R16: 51 vs 33 — rndne/cvt/ldexp are quarter-rate specials too).
// Null/failed levers (evidence): ILP prefetch (R8 null), occupancy 7->8
// blocks/CU (R18 null), poly exp2 (R16 +15us), bf16 LDS pack (R13/R17
// scratch blowup), coop single-kernel (R11 spill 293us), lb(256,8) (R13).
// Residual tail: bn memory pass ~8us + fin ~1.5 + gaps — only lever is
// grid-wide fusion, twice proven codegen-pathological on this toolchain.
//  1) kc_kernel:  gather fea, kc -> out + fused per-block stats partials
//     (packed v_pk_fma chains, v_exp_f32, conflict-free [4][64][17] tile).
//  2) fin_kernel: 64 blocks: reduce 2048 partials -> scale/shift.
//  3) bn_kernel:  in-place float4 y = relu(kc*scale + shift).

#define NFACES 16384
#define BATCH  8
#define KK     64
#define NBLK   2048            // kc grid: BATCH * (NFACES/64)

typedef float v2f __attribute__((ext_vector_type(2)));

// C = -1/(2*sigma^2) * log2(e)  with sigma = 0.2
__device__ __constant__ const float C_SCALE = -18.033688011112043f;

__global__ __launch_bounds__(256, 7) void kc_kernel(
    const float* __restrict__ normals,   // [B,3,N]
    const int*   __restrict__ nbr,       // [B,N,3]
    const float* __restrict__ walpha,    // [K*4]
    const float* __restrict__ wbeta,     // [K*4]
    float*       __restrict__ out,       // [B,K,N]
    float*       __restrict__ psum,      // [K][NBLK]
    float*       __restrict__ psumsq)    // [K][NBLK]
{
    __shared__ float4 sW[KK * 4];        // (m2*wx, m2*wy, m2*wz, 0)
    __shared__ float  sT[4][64][17];     // [wave][lane][k] transpose tile

    const int tid = threadIdx.x;

    // Kernel-point table: 256 threads -> 256 (k,j) entries
    {
        float a = walpha[tid];
        float b = wbeta[tid];
        float sa = sinf(a), ca = cosf(a);
        float sb = sinf(b), cb = cosf(b);
        const float m2 = -2.0f * C_SCALE;
        sW[tid] = make_float4(m2 * sa * cb, m2 * sa * sb, m2 * ca, 0.0f);
    }
    __syncthreads();

    const int b    = blockIdx.x >> 8;
    const int lane = tid & 63;
    const int n    = ((blockIdx.x & 255) << 6) + lane;
    const int kq   = tid >> 6;

    const float* nb_ = normals + (size_t)b * 3 * NFACES;
    float fx[4], fy[4], fz[4];
    fx[0] = nb_[n];
    fy[0] = nb_[NFACES + n];
    fz[0] = nb_[2 * NFACES + n];
    const int* ip = nbr + ((size_t)b * NFACES + n) * 3;
#pragma unroll
    for (int j = 0; j < 3; ++j) {
        int idx = ip[j];
        fx[j + 1] = nb_[idx];
        fy[j + 1] = nb_[NFACES + idx];
        fz[j + 1] = nb_[2 * NFACES + idx];
    }

    // Pack the 4 fea points into float2 pairs for v_pk_fma_f32.
    v2f fx01 = {fx[0], fx[1]}, fx23 = {fx[2], fx[3]};
    v2f fy01 = {fy[0], fy[1]}, fy23 = {fy[2], fy[3]};
    v2f fz01 = {fz[0], fz[1]}, fz23 = {fz[2], fz[3]};
    // fa_i = C*(|f_i|^2 + |w|^2), |w|^2 == 1 (to 1ulp)  — chain init
    v2f fa01, fa23;
    {
        v2f n01 = fx01 * fx01 + fy01 * fy01 + fz01 * fz01;
        v2f n23 = fx23 * fx23 + fy23 * fy23 + fz23 * fz23;
        fa01 = (v2f){C_SCALE, C_SCALE} * n01 + (v2f){C_SCALE, C_SCALE};
        fa23 = (v2f){C_SCALE, C_SCALE} * n23 + (v2f){C_SCALE, C_SCALE};
    }

    float* outp = out + ((size_t)b * KK + kq * 16) * NFACES + n;
    const float4* wp = &sW[kq * 64];

#pragma unroll
    for (int kk = 0; kk < 16; ++kk) {
        float s0 = 0.0f, s1 = 0.0f, s2 = 0.0f, s3 = 0.0f;
#pragma unroll
        for (int j = 0; j < 4; ++j) {
            float4 w = wp[kk * 4 + j];
            v2f wx = {w.x, w.x}, wy = {w.y, w.y}, wz = {w.z, w.z};
            v2f t01 = __builtin_elementwise_fma(wx, fx01,
                        __builtin_elementwise_fma(wy, fy01,
                          __builtin_elementwise_fma(wz, fz01, fa01)));
            v2f t23 = __builtin_elementwise_fma(wx, fx23,
                        __builtin_elementwise_fma(wy, fy23,
                          __builtin_elementwise_fma(wz, fz23, fa23)));
            s0 += __builtin_amdgcn_exp2f(t01.x);
            s1 += __builtin_amdgcn_exp2f(t01.y);
            s2 += __builtin_amdgcn_exp2f(t23.x);
            s3 += __builtin_amdgcn_exp2f(t23.y);
        }
        float kc = ((s0 + s1) + (s2 + s3)) * 0.0625f;
        outp[(size_t)kk * NFACES] = kc;
        sT[kq][lane][kk] = kc;               // intra-wave: no barrier needed
    }

    // Per-wave transpose reduce (reads exactly 2-way -> free).
    {
        const int kk = lane & 15, seg = lane >> 4;
        float v = 0.0f, q = 0.0f;
#pragma unroll
        for (int j = 0; j < 16; ++j) {
            float x = sT[kq][seg * 16 + j][kk];
            v += x;
            q = __builtin_fmaf(x, x, q);
        }
        v += __shfl_xor(v, 16, 64);  q += __shfl_xor(q, 16, 64);
        v += __shfl_xor(v, 32, 64);  q += __shfl_xor(q, 32, 64);
        if (seg == 0) {
            const int k = kq * 16 + kk;
            psum[(size_t)k * NBLK + blockIdx.x]   = v;
            psumsq[(size_t)k * NBLK + blockIdx.x] = q;
        }
    }
}

// One block per k: reduce 2048 partials -> scale/shift.
__global__ __launch_bounds__(256) void fin_kernel(
    const float* __restrict__ psum,
    const float* __restrict__ psumsq,
    const float* __restrict__ gamma,
    const float* __restrict__ beta,
    float*       __restrict__ scale,
    float*       __restrict__ shift)
{
    const int k = blockIdx.x;
    const int tid = threadIdx.x;
    const float4* ps = reinterpret_cast<const float4*>(psum   + (size_t)k * NBLK);
    const float4* pq = reinterpret_cast<const float4*>(psumsq + (size_t)k * NBLK);

    float s = 0.0f, q = 0.0f;
#pragma unroll
    for (int i = 0; i < 2; ++i) {
        float4 a = ps[i * 256 + tid];
        float4 c = pq[i * 256 + tid];
        s += (a.x + a.y) + (a.z + a.w);
        q += (c.x + c.y) + (c.z + c.w);
    }

    __shared__ float sS[4], sQ[4];
#pragma unroll
    for (int off = 32; off > 0; off >>= 1) {
        s += __shfl_down(s, off, 64);
        q += __shfl_down(q, off, 64);
    }
    const int lane = tid & 63, wid = tid >> 6;
    if (lane == 0) { sS[wid] = s; sQ[wid] = q; }
    __syncthreads();
    if (tid == 0) {
        float sum = (sS[0] + sS[1]) + (sS[2] + sS[3]);
        float sq  = (sQ[0] + sQ[1]) + (sQ[2] + sQ[3]);
        const float invN = 1.0f / (float)(BATCH * NFACES);
        float mean = sum * invN;
        float var  = sq * invN - mean * mean;
        float sc = gamma[k] / sqrtf(var + 1e-5f);
        scale[k] = sc;
        shift[k] = beta[k] - mean * sc;
    }
}

__global__ __launch_bounds__(256) void bn_kernel(
    float* __restrict__ out,
    const float* __restrict__ scale,
    const float* __restrict__ shift)
{
    const size_t idx = (size_t)blockIdx.x * 256 + threadIdx.x;
    const int k = (int)((idx >> 12) & 63);
    float4 v = reinterpret_cast<float4*>(out)[idx];
    const float sc = scale[k], sh = shift[k];
    v.x = fmaxf(__builtin_fmaf(v.x, sc, sh), 0.0f);
    v.y = fmaxf(__builtin_fmaf(v.y, sc, sh), 0.0f);
    v.z = fmaxf(__builtin_fmaf(v.z, sc, sh), 0.0f);
    v.w = fmaxf(__builtin_fmaf(v.w, sc, sh), 0.0f);
    reinterpret_cast<float4*>(out)[idx] = v;
}

extern "C" void kernel_launch(void* const* d_in, const int* in_sizes, int n_in,
                              void* d_out, int out_size, void* d_ws, size_t ws_size,
                              hipStream_t stream) {
    const float* normals = (const float*)d_in[0];
    const int*   nbr     = (const int*)d_in[1];
    const float* walpha  = (const float*)d_in[2];
    const float* wbeta   = (const float*)d_in[3];
    const float* gamma   = (const float*)d_in[4];
    const float* beta    = (const float*)d_in[5];
    float* out = (float*)d_out;

    float* psum   = (float*)d_ws;              // [64][2048]
    float* psumsq = psum + KK * NBLK;          // [64][2048]
    float* scale  = psumsq + KK * NBLK;        // [64]
    float* shift  = scale + KK;                // [64]

    kc_kernel<<<NBLK, 256, 0, stream>>>(normals, nbr, walpha, wbeta, out, psum, psumsq);
    fin_kernel<<<KK, 256, 0, stream>>>(psum, psumsq, gamma, beta, scale, shift);

    const int total_f4 = (BATCH * KK * NFACES) / 4;   // 2,097,152
    bn_kernel<<<total_f4 / 256, 256, 0, stream>>>(out, scale, shift);
}